// Round 4
// baseline (468.474 us; speedup 1.0000x reference)
//
#include <hip/hip_runtime.h>
#include <math.h>

// Problem constants
constexpr int B   = 16;
constexpr int C   = 256;
constexpr int H   = 64;
constexpr int W   = 64;
constexpr int K   = 4;
constexpr int O   = 256;
constexpr int HID = 65;
constexpr float TEMP = 34.0f;

typedef __bf16 bf16x8 __attribute__((ext_vector_type(8)));
typedef float  f32x16 __attribute__((ext_vector_type(16)));
typedef unsigned short ushort_t;

__device__ inline ushort_t f2bf(float f) {
    union { float f; unsigned u; } v; v.f = f;
    unsigned u = v.u;
    u += 0x7FFF + ((u >> 16) & 1);       // RNE
    return (ushort_t)(u >> 16);
}

__device__ inline void gl2lds16(const void* g, void* l) {
    __builtin_amdgcn_global_load_lds(
        (const __attribute__((address_space(1))) unsigned int*)g,
        (__attribute__((address_space(3))) unsigned int*)l, 16, 0, 0);
}

// ---------------------------------------------------------------------------
// tp v2: transpose x -> xT[b][ci][y][w][c16] (bf16) + per-block pool partials.
// grid (ci=16, yg=4, b=16), 256 thr. Coalesced float4 reads (4 rows x 256B =
// 1KB/wave-instr), natural-layout LDS (b64 writes), coalesced uint4 stores.
// pooled_part[yg][b][c] written without atomics (summed in attention).
// ---------------------------------------------------------------------------
__global__ void tp_kernel(const float* __restrict__ x,
                          ushort_t* __restrict__ xT,
                          float* __restrict__ pooled_part) {
    const int ci = blockIdx.x, yg = blockIdx.y, b = blockIdx.z;
    const int tid = threadIdx.x;
    const int wv  = tid >> 6, lane = tid & 63;

    __shared__ ushort_t t_lds[16 * 1024];    // [c][y][w] bf16, 32 KB
    __shared__ float pw[16][4];

    const int yy = tid >> 4;                 // 0..15
    const int w4 = tid & 15;                 // float4 index

    #pragma unroll
    for (int c = 0; c < 16; ++c) {
        const float4 v = *(const float4*)(x
            + (((size_t)b * C + ci * 16 + c) * H + yg * 16 + yy) * W + w4 * 4);
        float s = (v.x + v.y) + (v.z + v.w);
        union { ushort_t u[4]; uint2 p; } pk;
        pk.u[0] = f2bf(v.x); pk.u[1] = f2bf(v.y);
        pk.u[2] = f2bf(v.z); pk.u[3] = f2bf(v.w);
        *(uint2*)&t_lds[c * 1024 + yy * 64 + w4 * 4] = pk.p;
        #pragma unroll
        for (int off = 32; off > 0; off >>= 1) s += __shfl_down(s, off, 64);
        if (lane == 0) pw[c][wv] = s;
    }
    __syncthreads();

    if (tid < 16)
        pooled_part[((size_t)yg * B + b) * C + ci * 16 + tid] =
            (pw[tid][0] + pw[tid][1] + pw[tid][2] + pw[tid][3]) * (1.0f / (H * W));

    // store: 2048 uint4 over 8 iters; lane-consecutive -> 16B-consecutive
    #pragma unroll
    for (int it = 0; it < 8; ++it) {
        const int idx  = it * 256 + tid;
        const int y    = idx >> 7;
        const int rem  = idx & 127;
        const int w    = rem >> 1;
        const int half = rem & 1;
        union { ushort_t u[8]; uint4 v; } pk;
        #pragma unroll
        for (int j = 0; j < 8; ++j)
            pk.u[j] = t_lds[(half * 8 + j) * 1024 + y * 64 + w];
        *(uint4*)(xT + (((size_t)(b * 16 + ci) * 64 + yg * 16 + y) * 1024)
                  + w * 16 + half * 8) = pk.v;
    }
}

// ---------------------------------------------------------------------------
// Attention: sums 4 pool partials, float4 w_fc1 reads.  grid=B, 128 thr.
// ---------------------------------------------------------------------------
__global__ void attention_kernel(const float* __restrict__ pooled_part,
                                 const float* __restrict__ w_fc1,
                                 const float* __restrict__ w_fc2,
                                 const float* __restrict__ b_fc2,
                                 float* __restrict__ att) {
    const int b = blockIdx.x;
    const int tid = threadIdx.x;
    __shared__ float pool_s[C];
    __shared__ float h_s[HID];
    __shared__ float logit_s[K];

    for (int i = tid; i < C; i += 128)
        pool_s[i] = pooled_part[((size_t)0 * B + b) * C + i]
                  + pooled_part[((size_t)1 * B + b) * C + i]
                  + pooled_part[((size_t)2 * B + b) * C + i]
                  + pooled_part[((size_t)3 * B + b) * C + i];
    __syncthreads();

    if (tid < HID) {
        const float4* wr = (const float4*)(w_fc1 + (size_t)tid * C);
        float s = 0.f;
        #pragma unroll 8
        for (int c4 = 0; c4 < C / 4; ++c4) {
            float4 wv = wr[c4];
            const float* p = &pool_s[c4 * 4];
            s += wv.x * p[0] + wv.y * p[1] + wv.z * p[2] + wv.w * p[3];
        }
        h_s[tid] = fmaxf(s, 0.f);
    }
    __syncthreads();
    if (tid < K) {
        const float* wr = w_fc2 + (size_t)tid * HID;
        float s = b_fc2[tid];
        for (int j = 0; j < HID; ++j) s += h_s[j] * wr[j];
        logit_s[tid] = s * (1.0f / TEMP);
    }
    __syncthreads();
    if (tid == 0) {
        float m = fmaxf(fmaxf(logit_s[0], logit_s[1]), fmaxf(logit_s[2], logit_s[3]));
        float e0 = expf(logit_s[0] - m), e1 = expf(logit_s[1] - m);
        float e2 = expf(logit_s[2] - m), e3 = expf(logit_s[3] - m);
        float inv = 1.0f / (e0 + e1 + e2 + e3);
        att[b * K + 0] = e0 * inv; att[b * K + 1] = e1 * inv;
        att[b * K + 2] = e2 * inv; att[b * K + 3] = e3 * inv;
    }
}

// ---------------------------------------------------------------------------
// wagg v2: stage weight[k][o][*] coalesced into LDS, then aggregate+pack.
// Output layout = MFMA A-frag lane order: wagg_sw[b][ci][t][mi][lane][j8].
// grid=O blocks, 256 thr.
// ---------------------------------------------------------------------------
__global__ void wagg_kernel(const float* __restrict__ weight,
                            const float* __restrict__ att,
                            ushort_t* __restrict__ wagg_sw) {
    const int o = blockIdx.x;
    const int tid = threadIdx.x;

    __shared__ float w_lds[4][2304];     // 36,864 B
    __shared__ float att_s[B * K];

    #pragma unroll
    for (int k = 0; k < 4; ++k) {
        const float4* src = (const float4*)(weight + ((size_t)(k * O + o)) * 2304);
        for (int i = tid; i < 576; i += 256)
            ((float4*)w_lds[k])[i] = src[i];
    }
    if (tid < B * K) att_s[tid] = att[tid];
    __syncthreads();

    const int oct = tid >> 3;            // c octet 0..31
    const int bg  = tid & 7;             // b pair
    const int mi   = o >> 5;
    const int lm   = o & 31;
    const int ci   = oct >> 1;
    const int half = oct & 1;
    const int lane = half * 32 + lm;

    for (int t = 0; t < 9; ++t) {
        float w0[8], w1[8], w2[8], w3[8];
        #pragma unroll
        for (int j = 0; j < 8; ++j) {
            const int cidx = (oct * 8 + j) * 9 + t;
            w0[j] = w_lds[0][cidx]; w1[j] = w_lds[1][cidx];
            w2[j] = w_lds[2][cidx]; w3[j] = w_lds[3][cidx];
        }
        #pragma unroll
        for (int bb = 0; bb < 2; ++bb) {
            const int bs = bg * 2 + bb;
            const float a0 = att_s[bs * K + 0], a1 = att_s[bs * K + 1];
            const float a2 = att_s[bs * K + 2], a3 = att_s[bs * K + 3];
            union { ushort_t u[8]; uint4 v; } pk;
            #pragma unroll
            for (int j = 0; j < 8; ++j)
                pk.u[j] = f2bf(a0 * w0[j] + a1 * w1[j] + a2 * w2[j] + a3 * w3[j]);
            size_t idx = ((((size_t)bs * 16 + ci) * 9 + t) * 8 + mi) * 512 + lane * 8;
            *(uint4*)&wagg_sw[idx] = pk.v;
        }
    }
}

// ---------------------------------------------------------------------------
// conv v3: 32x32x16 MFMA. A-frags loaded global->VGPR (2-slot, 2-tap
// lookahead pipeline) — no LDS, no barrier dependency. LDS holds x only,
// double-buffered (2 x 12,672 B), 1 barrier/chunk.
// grid (b=16, yt=16, oz=2), 256 thr.
// ---------------------------------------------------------------------------
__global__ __launch_bounds__(256, 2)
void conv_mfma_kernel(const ushort_t* __restrict__ xT,
                      const ushort_t* __restrict__ wagg_sw,
                      const float* __restrict__ bias,
                      const float* __restrict__ att,
                      float* __restrict__ out) {
    const int b  = blockIdx.x;
    const int yt = blockIdx.y;
    const int oz = blockIdx.z;
    const int y0 = yt * 4;

    const int tid  = threadIdx.x;
    const int lane = tid & 63;
    const int wid  = tid >> 6;
    const int n16  = lane & 31;
    const int khalf = lane >> 5;

    __shared__ __align__(16) ushort_t x_lds[2][6 * 66 * 16];   // 2 x 12,672 B

    for (int i = tid; i < 2 * 6336; i += 256) ((ushort_t*)x_lds)[i] = 0;
    __syncthreads();                    // halos zeroed before first stage

    // A-frag base: uint4 index (((b*16+ci)*9+t)*8 + oz*4 + a)*64 + lane
    const uint4* A_base = (const uint4*)wagg_sw
        + ((((size_t)b * 16) * 9) * 8 + (size_t)oz * 4) * 64 + lane;

    f32x16 acc[4][2];
    #pragma unroll
    for (int a = 0; a < 4; ++a)
        #pragma unroll
        for (int ni = 0; ni < 2; ++ni)
            acc[a][ni] = (f32x16)(0.f);

    auto stage_x = [&](int ci, int bufp) {
        for (int i = wid; i < 12; i += 4) {
            const int r = i >> 1, hh = i & 1;
            const int y = y0 - 1 + r;
            if ((unsigned)y < (unsigned)H) {
                const ushort_t* g = xT + (((size_t)(b * 16 + ci) * 64 + y) * 1024)
                                  + hh * 512 + lane * 8;
                gl2lds16(g, &x_lds[bufp][r * 1056 + 16 + hh * 512]);
            }
        }
    };

    union AFrag { uint4 u[4]; bf16x8 h[4]; };
    AFrag aslot[2];
    auto aload = [&](int slot, int s) {          // s = ci*9 + t
        const uint4* g = A_base + (size_t)s * 8 * 64;
        #pragma unroll
        for (int a = 0; a < 4; ++a) aslot[slot].u[a] = g[a * 64];
    };

    stage_x(0, 0);
    aload(0, 0);
    aload(1, 1);
    __syncthreads();

    for (int ci = 0; ci < 16; ++ci) {
        if (ci < 15) stage_x(ci + 1, (ci + 1) & 1);
        const int bufp = ci & 1;
        #pragma unroll
        for (int t = 0; t < 9; ++t) {
            const int s = ci * 9 + t;
            const int slot = s & 1;
            const int dy = t / 3, dx = t % 3;
            const int r = wid + dy;

            bf16x8 bfv[2];
            #pragma unroll
            for (int ni = 0; ni < 2; ++ni)
                bfv[ni] = *(const bf16x8*)&x_lds[bufp][r * 1056
                           + (ni * 32 + n16 + dx) * 16 + khalf * 8];
            bf16x8 afv[4];
            #pragma unroll
            for (int a = 0; a < 4; ++a) afv[a] = aslot[slot].h[a];

            if (s + 2 < 144) aload(slot, s + 2);     // 2-tap lookahead

            #pragma unroll
            for (int a = 0; a < 4; ++a) {
                acc[a][0] = __builtin_amdgcn_mfma_f32_32x32x16_bf16(afv[a], bfv[0], acc[a][0], 0, 0, 0);
                acc[a][1] = __builtin_amdgcn_mfma_f32_32x32x16_bf16(afv[a], bfv[1], acc[a][1], 0, 0, 0);
            }
        }
        __syncthreads();
    }

    // epilogue: aggregated bias via LDS, then store
    float* aggb = (float*)x_lds;
    if (tid < 128) {
        const int o = oz * 128 + tid;
        aggb[tid] = att[b * K + 0] * bias[0 * O + o] + att[b * K + 1] * bias[1 * O + o]
                  + att[b * K + 2] * bias[2 * O + o] + att[b * K + 3] * bias[3 * O + o];
    }
    __syncthreads();

    const int y = y0 + wid;
    #pragma unroll
    for (int a = 0; a < 4; ++a) {
        #pragma unroll
        for (int ni = 0; ni < 2; ++ni) {
            #pragma unroll
            for (int reg = 0; reg < 16; ++reg) {
                const int row = (reg & 3) + 8 * (reg >> 2) + 4 * khalf;
                const int ol  = a * 32 + row;
                out[(((size_t)b * O + oz * 128 + ol) * H + y) * W + ni * 32 + n16]
                    = acc[a][ni][reg] + aggb[ol];
            }
        }
    }
}

// ---------------------------------------------------------------------------
// Fallback fp32 path (round-1, known-correct) if ws too small.
// ---------------------------------------------------------------------------
__global__ void pool_kernel(const float* __restrict__ x, float* __restrict__ pooled) {
    const int bc = blockIdx.x;
    const float4* p4 = (const float4*)(x + (size_t)bc * (H * W));
    const int tid = threadIdx.x;
    float s = 0.f;
    #pragma unroll
    for (int i = 0; i < (H * W / 4) / 256; ++i) {
        float4 v = p4[tid + i * 256];
        s += (v.x + v.y) + (v.z + v.w);
    }
    #pragma unroll
    for (int off = 32; off > 0; off >>= 1) s += __shfl_down(s, off, 64);
    __shared__ float red[4];
    if ((tid & 63) == 0) red[tid >> 6] = s;
    __syncthreads();
    if (tid == 0) pooled[bc] = ((red[0] + red[1]) + (red[2] + red[3])) * (1.0f / (H * W));
}

__global__ void attention_fb_kernel(const float* __restrict__ pooled,
                                    const float* __restrict__ w_fc1,
                                    const float* __restrict__ w_fc2,
                                    const float* __restrict__ b_fc2,
                                    float* __restrict__ att) {
    const int b = blockIdx.x;
    const int tid = threadIdx.x;
    __shared__ float pool_s[C];
    __shared__ float h_s[HID];
    __shared__ float logit_s[K];
    for (int i = tid; i < C; i += 128) pool_s[i] = pooled[b * C + i];
    __syncthreads();
    if (tid < HID) {
        const float* wr = w_fc1 + (size_t)tid * C;
        float s = 0.f;
        for (int c = 0; c < C; ++c) s += pool_s[c] * wr[c];
        h_s[tid] = fmaxf(s, 0.f);
    }
    __syncthreads();
    if (tid < K) {
        const float* wr = w_fc2 + (size_t)tid * HID;
        float s = b_fc2[tid];
        for (int j = 0; j < HID; ++j) s += h_s[j] * wr[j];
        logit_s[tid] = s * (1.0f / TEMP);
    }
    __syncthreads();
    if (tid == 0) {
        float m = fmaxf(fmaxf(logit_s[0], logit_s[1]), fmaxf(logit_s[2], logit_s[3]));
        float e0 = expf(logit_s[0] - m), e1 = expf(logit_s[1] - m);
        float e2 = expf(logit_s[2] - m), e3 = expf(logit_s[3] - m);
        float inv = 1.0f / (e0 + e1 + e2 + e3);
        att[b * K + 0] = e0 * inv; att[b * K + 1] = e1 * inv;
        att[b * K + 2] = e2 * inv; att[b * K + 3] = e3 * inv;
    }
}

constexpr int TILE_H = 32;
constexpr int TILE_W = 64;
constexpr int CCF = 4, OT = 8, PX = 8;
constexpr int XS_STRIDE = TILE_W + 3;

__global__ __launch_bounds__(256, 2)
void conv_kernel(const float* __restrict__ x, const float* __restrict__ weight,
                 const float* __restrict__ bias, const float* __restrict__ att,
                 float* __restrict__ out) {
    const int tile_y = blockIdx.x, o0 = blockIdx.y * OT, b = blockIdx.z;
    const int tid = threadIdx.x, tx = tid & 7, ty = tid >> 3, ty0 = tile_y * TILE_H;
    __shared__ __align__(16) float xs[CCF][TILE_H + 2][XS_STRIDE];
    __shared__ __align__(16) float ws_s[OT][CCF][12];
    const float a0 = att[b * K + 0], a1 = att[b * K + 1];
    const float a2 = att[b * K + 2], a3 = att[b * K + 3];
    float acc[OT][PX];
    #pragma unroll
    for (int o = 0; o < OT; ++o)
        #pragma unroll
        for (int p = 0; p < PX; ++p) acc[o][p] = 0.f;
    const float* xb = x + (size_t)b * C * H * W;
    constexpr int X_ELEMS = CCF * (TILE_H + 2) * (TILE_W + 2);
    constexpr int W_ELEMS = OT * CCF * 9;
    for (int c0 = 0; c0 < C; c0 += CCF) {
        __syncthreads();
        for (int idx = tid; idx < X_ELEMS; idx += 256) {
            int cc = idx / ((TILE_H + 2) * (TILE_W + 2));
            int rem = idx - cc * ((TILE_H + 2) * (TILE_W + 2));
            int r = rem / (TILE_W + 2), col = rem - r * (TILE_W + 2);
            int gy = ty0 - 1 + r, gx = col - 1;
            float v = 0.f;
            if ((unsigned)gy < (unsigned)H && (unsigned)gx < (unsigned)W)
                v = xb[((size_t)(c0 + cc) * H + gy) * W + gx];
            xs[cc][r][col] = v;
        }
        for (int idx = tid; idx < W_ELEMS; idx += 256) {
            int o = idx / (CCF * 9), rem = idx - o * (CCF * 9);
            int cc = rem / 9, tap = rem - cc * 9;
            size_t base = ((size_t)(o0 + o) * C + (c0 + cc)) * 9 + tap;
            ws_s[o][cc][tap] = a0 * weight[base] + a1 * weight[(size_t)1 * O * C * 9 + base]
                             + a2 * weight[(size_t)2 * O * C * 9 + base]
                             + a3 * weight[(size_t)3 * O * C * 9 + base];
        }
        __syncthreads();
        #pragma unroll
        for (int cc = 0; cc < CCF; ++cc) {
            float xv[3][10];
            #pragma unroll
            for (int dy = 0; dy < 3; ++dy)
                #pragma unroll
                for (int j = 0; j < 10; ++j) xv[dy][j] = xs[cc][ty + dy][8 * tx + j];
            #pragma unroll
            for (int o = 0; o < OT; ++o) {
                float4 w0 = *(const float4*)&ws_s[o][cc][0];
                float4 w1 = *(const float4*)&ws_s[o][cc][4];
                float w8 = ws_s[o][cc][8];
                #pragma unroll
                for (int p = 0; p < PX; ++p) {
                    float s = acc[o][p];
                    s = fmaf(xv[0][p + 0], w0.x, s); s = fmaf(xv[0][p + 1], w0.y, s);
                    s = fmaf(xv[0][p + 2], w0.z, s); s = fmaf(xv[1][p + 0], w0.w, s);
                    s = fmaf(xv[1][p + 1], w1.x, s); s = fmaf(xv[1][p + 2], w1.y, s);
                    s = fmaf(xv[2][p + 0], w1.z, s); s = fmaf(xv[2][p + 1], w1.w, s);
                    s = fmaf(xv[2][p + 2], w8, s);
                    acc[o][p] = s;
                }
            }
        }
    }
    const int oy = ty0 + ty, ox = 8 * tx;
    #pragma unroll
    for (int o = 0; o < OT; ++o) {
        float ab = a0 * bias[0 * O + o0 + o] + a1 * bias[1 * O + o0 + o]
                 + a2 * bias[2 * O + o0 + o] + a3 * bias[3 * O + o0 + o];
        float4 v0 = make_float4(acc[o][0] + ab, acc[o][1] + ab, acc[o][2] + ab, acc[o][3] + ab);
        float4 v1 = make_float4(acc[o][4] + ab, acc[o][5] + ab, acc[o][6] + ab, acc[o][7] + ab);
        float* op = out + (((size_t)b * O + (o0 + o)) * H + oy) * W + ox;
        *(float4*)(op) = v0; *(float4*)(op + 4) = v1;
    }
}

// ---------------------------------------------------------------------------
extern "C" void kernel_launch(void* const* d_in, const int* in_sizes, int n_in,
                              void* d_out, int out_size, void* d_ws, size_t ws_size,
                              hipStream_t stream) {
    const float* x      = (const float*)d_in[0];
    const float* w_fc1  = (const float*)d_in[1];
    const float* w_fc2  = (const float*)d_in[2];
    const float* b_fc2  = (const float*)d_in[3];
    const float* weight = (const float*)d_in[4];
    const float* bias   = (const float*)d_in[5];
    float* out = (float*)d_out;

    float* pooled_part = (float*)d_ws;                       // 4*B*C fp32 = 64 KB
    float* att = (float*)((char*)d_ws + 64 * 1024);          // B*K fp32
    ushort_t* wagg_sw = (ushort_t*)((char*)d_ws + 128 * 1024);
    const size_t wagg_bytes = (size_t)B * 16 * 9 * 8 * 512 * 2;      // 18,874,368
    ushort_t* xT = (ushort_t*)((char*)wagg_sw + wagg_bytes);
    const size_t xT_bytes = (size_t)B * 16 * 64 * 64 * 16 * 2;       // 33,554,432
    const size_t needed = 128 * 1024 + wagg_bytes + xT_bytes;

    if (ws_size >= needed) {
        tp_kernel<<<dim3(16, 4, B), dim3(256), 0, stream>>>(x, xT, pooled_part);
        attention_kernel<<<dim3(B), dim3(128), 0, stream>>>(pooled_part, w_fc1, w_fc2, b_fc2, att);
        wagg_kernel<<<dim3(O), dim3(256), 0, stream>>>(weight, att, wagg_sw);
        conv_mfma_kernel<<<dim3(B, 16, 2), dim3(256), 0, stream>>>(xT, wagg_sw, bias, att, out);
    } else {
        float* pooled = (float*)d_ws;
        pool_kernel<<<dim3(B * C), dim3(256), 0, stream>>>(x, pooled);
        attention_fb_kernel<<<dim3(B), dim3(128), 0, stream>>>(pooled, w_fc1, w_fc2, b_fc2, att);
        conv_kernel<<<dim3(H / TILE_H, O / OT, B), dim3(256), 0, stream>>>(x, weight, bias, att, out);
    }
}

// Round 5
// 236.664 us; speedup vs baseline: 1.9795x; 1.9795x over previous
//
#include <hip/hip_runtime.h>
#include <math.h>

// Problem constants
constexpr int B   = 16;
constexpr int C   = 256;
constexpr int H   = 64;
constexpr int W   = 64;
constexpr int K   = 4;
constexpr int O   = 256;
constexpr int HID = 65;
constexpr float TEMP = 34.0f;

typedef __bf16 bf16x8 __attribute__((ext_vector_type(8)));
typedef float  f32x16 __attribute__((ext_vector_type(16)));
typedef unsigned short ushort_t;

__device__ inline ushort_t f2bf(float f) {
    union { float f; unsigned u; } v; v.f = f;
    unsigned u = v.u;
    u += 0x7FFF + ((u >> 16) & 1);       // RNE
    return (ushort_t)(u >> 16);
}

// ---------------------------------------------------------------------------
// Pool: pooled[b,c] = mean(x[b,c,:,:]).  grid = B*C blocks, 256 thr.
// ---------------------------------------------------------------------------
__global__ void pool_kernel(const float* __restrict__ x, float* __restrict__ pooled) {
    const int bc = blockIdx.x;
    const float4* p4 = (const float4*)(x + (size_t)bc * (H * W));
    const int tid = threadIdx.x;
    float s = 0.f;
    #pragma unroll
    for (int i = 0; i < (H * W / 4) / 256; ++i) {
        float4 v = p4[tid + i * 256];
        s += (v.x + v.y) + (v.z + v.w);
    }
    #pragma unroll
    for (int off = 32; off > 0; off >>= 1) s += __shfl_down(s, off, 64);
    __shared__ float red[4];
    if ((tid & 63) == 0) red[tid >> 6] = s;
    __syncthreads();
    if (tid == 0) pooled[bc] = ((red[0] + red[1]) + (red[2] + red[3])) * (1.0f / (H * W));
}

// ---------------------------------------------------------------------------
// Attention.  grid=B, 128 thr.
// ---------------------------------------------------------------------------
__global__ void attention_kernel(const float* __restrict__ pooled,
                                 const float* __restrict__ w_fc1,
                                 const float* __restrict__ w_fc2,
                                 const float* __restrict__ b_fc2,
                                 float* __restrict__ att) {
    const int b = blockIdx.x;
    const int tid = threadIdx.x;
    __shared__ float pool_s[C];
    __shared__ float h_s[HID];
    __shared__ float logit_s[K];

    for (int i = tid; i < C; i += 128) pool_s[i] = pooled[b * C + i];
    __syncthreads();
    if (tid < HID) {
        const float4* wr = (const float4*)(w_fc1 + (size_t)tid * C);
        float s = 0.f;
        #pragma unroll 8
        for (int c4 = 0; c4 < C / 4; ++c4) {
            float4 wv = wr[c4];
            const float* p = &pool_s[c4 * 4];
            s += wv.x * p[0] + wv.y * p[1] + wv.z * p[2] + wv.w * p[3];
        }
        h_s[tid] = fmaxf(s, 0.f);
    }
    __syncthreads();
    if (tid < K) {
        const float* wr = w_fc2 + (size_t)tid * HID;
        float s = b_fc2[tid];
        for (int j = 0; j < HID; ++j) s += h_s[j] * wr[j];
        logit_s[tid] = s * (1.0f / TEMP);
    }
    __syncthreads();
    if (tid == 0) {
        float m = fmaxf(fmaxf(logit_s[0], logit_s[1]), fmaxf(logit_s[2], logit_s[3]));
        float e0 = expf(logit_s[0] - m), e1 = expf(logit_s[1] - m);
        float e2 = expf(logit_s[2] - m), e3 = expf(logit_s[3] - m);
        float inv = 1.0f / (e0 + e1 + e2 + e3);
        att[b * K + 0] = e0 * inv; att[b * K + 1] = e1 * inv;
        att[b * K + 2] = e2 * inv; att[b * K + 3] = e3 * inv;
    }
}

// ---------------------------------------------------------------------------
// wagg: aggregate expert weights -> bf16 in MFMA A-frag lane order:
// wagg_sw[b][ci16][t9][mi8][lane64][j8],  lane=(c>>3&1)*32+(o&31), j=c&7.
// grid=O blocks, 256 thr; weight staged coalesced via LDS.
// ---------------------------------------------------------------------------
__global__ void wagg_kernel(const float* __restrict__ weight,
                            const float* __restrict__ att,
                            ushort_t* __restrict__ wagg_sw) {
    const int o = blockIdx.x;
    const int tid = threadIdx.x;

    __shared__ float w_lds[4][2304];     // 36,864 B
    __shared__ float att_s[B * K];

    #pragma unroll
    for (int k = 0; k < 4; ++k) {
        const float4* src = (const float4*)(weight + ((size_t)(k * O + o)) * 2304);
        for (int i = tid; i < 576; i += 256)
            ((float4*)w_lds[k])[i] = src[i];
    }
    if (tid < B * K) att_s[tid] = att[tid];
    __syncthreads();

    const int oct = tid >> 3;            // c octet 0..31
    const int bg  = tid & 7;             // b pair
    const int mi   = o >> 5;
    const int lm   = o & 31;
    const int ci   = oct >> 1;
    const int half = oct & 1;
    const int lane = half * 32 + lm;

    for (int t = 0; t < 9; ++t) {
        float w0[8], w1[8], w2[8], w3[8];
        #pragma unroll
        for (int j = 0; j < 8; ++j) {
            const int cidx = (oct * 8 + j) * 9 + t;
            w0[j] = w_lds[0][cidx]; w1[j] = w_lds[1][cidx];
            w2[j] = w_lds[2][cidx]; w3[j] = w_lds[3][cidx];
        }
        #pragma unroll
        for (int bb = 0; bb < 2; ++bb) {
            const int bs = bg * 2 + bb;
            const float a0 = att_s[bs * K + 0], a1 = att_s[bs * K + 1];
            const float a2 = att_s[bs * K + 2], a3 = att_s[bs * K + 3];
            union { ushort_t u[8]; uint4 v; } pk;
            #pragma unroll
            for (int j = 0; j < 8; ++j)
                pk.u[j] = f2bf(a0 * w0[j] + a1 * w1[j] + a2 * w2[j] + a3 * w3[j]);
            size_t idx = ((((size_t)bs * 16 + ci) * 9 + t) * 8 + mi) * 512 + lane * 8;
            *(uint4*)&wagg_sw[idx] = pk.v;
        }
    }
}

// ---------------------------------------------------------------------------
// conv v5: 32x32x16 MFMA. A-frags global->VGPR with two STATICALLY-indexed
// slots (aE/aO, parity fixed by unrolling ci by 2 — no scratch). x staged
// in-kernel from raw fp32: global->VGPR->f2bf->ds_write_b128 (conflict-free),
// double-buffered, 2 barriers per chunk-pair.  grid (b=16, yt=16, oz=2).
// ---------------------------------------------------------------------------
__global__ __launch_bounds__(256, 2)
void conv_mfma_kernel(const float* __restrict__ x,
                      const ushort_t* __restrict__ wagg_sw,
                      const float* __restrict__ bias,
                      const float* __restrict__ att,
                      float* __restrict__ out) {
    const int b  = blockIdx.x;
    const int yt = blockIdx.y;
    const int oz = blockIdx.z;
    const int y0 = yt * 4;

    const int tid  = threadIdx.x;
    const int lane = tid & 63;
    const int wid  = tid >> 6;
    const int n16  = lane & 31;
    const int khalf = lane >> 5;

    __shared__ __align__(16) ushort_t x_lds[2][6 * 1056];   // [buf][r][col66][c16]

    for (int i = tid; i < 2 * 6336; i += 256) ((ushort_t*)x_lds)[i] = 0;

    // staging roles: wave -> (c-octet, row-third); lanes -> cols
    const int scol = lane;               // 0..63
    const int soct = wid & 1;            // c octet (8 channels)
    const int srh  = wid >> 1;           // rows srh*3 .. srh*3+2

    const uint4* A_base = (const uint4*)wagg_sw
        + (size_t)b * 73728 + (size_t)oz * 256 + lane;

    f32x16 acc[4][2];
    #pragma unroll
    for (int a = 0; a < 4; ++a)
        #pragma unroll
        for (int ni = 0; ni < 2; ++ni)
            acc[a][ni] = (f32x16)(0.f);

    float xv[3][8];
    auto gload = [&](int ci) {
        #pragma unroll
        for (int rr = 0; rr < 3; ++rr) {
            const int y = y0 - 1 + srh * 3 + rr;
            if ((unsigned)y < (unsigned)H) {
                const float* src = x + (((size_t)b * C + ci * 16 + soct * 8) * H + y) * W + scol;
                #pragma unroll
                for (int j = 0; j < 8; ++j)
                    xv[rr][j] = src[(size_t)j * H * W];
            }
        }
    };
    auto xwrite = [&](int buf) {
        #pragma unroll
        for (int rr = 0; rr < 3; ++rr) {
            const int r = srh * 3 + rr;
            const int y = y0 - 1 + r;
            if ((unsigned)y < (unsigned)H) {
                union { ushort_t u[8]; uint4 v; } pk;
                #pragma unroll
                for (int j = 0; j < 8; ++j) pk.u[j] = f2bf(xv[rr][j]);
                *(uint4*)&x_lds[buf][r * 1056 + (scol + 1) * 16 + soct * 8] = pk.v;
            }
        }
    };

    uint4 aE[4], aO[4];                  // static-indexed only!
    auto aload = [&](uint4 (&sl)[4], int s) {
        const uint4* g = A_base + (size_t)s * 512;
        #pragma unroll
        for (int a = 0; a < 4; ++a) sl[a] = g[a * 64];
    };
    auto tap = [&](uint4 (&sl)[4], int buf, int t, int s) {
        const int dy = t / 3, dx = t % 3;
        const int r = wid + dy;
        bf16x8 b0 = *(const bf16x8*)&x_lds[buf][r * 1056 + (n16 + dx) * 16 + khalf * 8];
        bf16x8 b1 = *(const bf16x8*)&x_lds[buf][r * 1056 + (32 + n16 + dx) * 16 + khalf * 8];
        #pragma unroll
        for (int a = 0; a < 4; ++a) {
            bf16x8 af = *(const bf16x8*)&sl[a];
            acc[a][0] = __builtin_amdgcn_mfma_f32_32x32x16_bf16(af, b0, acc[a][0], 0, 0, 0);
            acc[a][1] = __builtin_amdgcn_mfma_f32_32x32x16_bf16(af, b1, acc[a][1], 0, 0, 0);
        }
        if (s + 2 < 144) aload(sl, s + 2);   // prefetch after consumption
    };

    // prologue
    aload(aE, 0);
    aload(aO, 1);
    gload(0);
    __syncthreads();                     // zero-init visible before data writes
    xwrite(0);
    __syncthreads();                     // buf0 ready

    for (int cc = 0; cc < 8; ++cc) {
        const int ci0 = cc * 2;
        // even chunk (s parity == t parity), buf0
        gload(ci0 + 1);
        #pragma unroll
        for (int t = 0; t < 9; ++t) {
            const int s = ci0 * 9 + t;
            if (t & 1) tap(aO, 0, t, s); else tap(aE, 0, t, s);
        }
        xwrite(1);
        __syncthreads();
        // odd chunk (s parity == (t+1) parity), buf1
        if (ci0 + 2 < 16) gload(ci0 + 2);
        #pragma unroll
        for (int t = 0; t < 9; ++t) {
            const int s = (ci0 + 1) * 9 + t;
            if (t & 1) tap(aE, 1, t, s); else tap(aO, 1, t, s);
        }
        if (ci0 + 2 < 16) xwrite(0);
        __syncthreads();
    }

    // epilogue: aggregated bias via LDS, then store
    float* aggb = (float*)x_lds;
    if (tid < 128) {
        const int o = oz * 128 + tid;
        aggb[tid] = att[b * K + 0] * bias[0 * O + o] + att[b * K + 1] * bias[1 * O + o]
                  + att[b * K + 2] * bias[2 * O + o] + att[b * K + 3] * bias[3 * O + o];
    }
    __syncthreads();

    const int y = y0 + wid;
    #pragma unroll
    for (int a = 0; a < 4; ++a) {
        #pragma unroll
        for (int ni = 0; ni < 2; ++ni) {
            #pragma unroll
            for (int reg = 0; reg < 16; ++reg) {
                const int row = (reg & 3) + 8 * (reg >> 2) + 4 * khalf;
                const int ol  = a * 32 + row;
                out[(((size_t)b * O + oz * 128 + ol) * H + y) * W + ni * 32 + n16]
                    = acc[a][ni][reg] + aggb[ol];
            }
        }
    }
}

// ---------------------------------------------------------------------------
// Fallback fp32 direct conv (round-1, known-correct) if ws too small.
// ---------------------------------------------------------------------------
constexpr int TILE_H = 32;
constexpr int TILE_W = 64;
constexpr int CCF = 4, OT = 8, PX = 8;
constexpr int XS_STRIDE = TILE_W + 3;

__global__ __launch_bounds__(256, 2)
void conv_kernel(const float* __restrict__ x, const float* __restrict__ weight,
                 const float* __restrict__ bias, const float* __restrict__ att,
                 float* __restrict__ out) {
    const int tile_y = blockIdx.x, o0 = blockIdx.y * OT, b = blockIdx.z;
    const int tid = threadIdx.x, tx = tid & 7, ty = tid >> 3, ty0 = tile_y * TILE_H;
    __shared__ __align__(16) float xs[CCF][TILE_H + 2][XS_STRIDE];
    __shared__ __align__(16) float ws_s[OT][CCF][12];
    const float a0 = att[b * K + 0], a1 = att[b * K + 1];
    const float a2 = att[b * K + 2], a3 = att[b * K + 3];
    float acc[OT][PX];
    #pragma unroll
    for (int o = 0; o < OT; ++o)
        #pragma unroll
        for (int p = 0; p < PX; ++p) acc[o][p] = 0.f;
    const float* xb = x + (size_t)b * C * H * W;
    constexpr int X_ELEMS = CCF * (TILE_H + 2) * (TILE_W + 2);
    constexpr int W_ELEMS = OT * CCF * 9;
    for (int c0 = 0; c0 < C; c0 += CCF) {
        __syncthreads();
        for (int idx = tid; idx < X_ELEMS; idx += 256) {
            int cc = idx / ((TILE_H + 2) * (TILE_W + 2));
            int rem = idx - cc * ((TILE_H + 2) * (TILE_W + 2));
            int r = rem / (TILE_W + 2), col = rem - r * (TILE_W + 2);
            int gy = ty0 - 1 + r, gx = col - 1;
            float v = 0.f;
            if ((unsigned)gy < (unsigned)H && (unsigned)gx < (unsigned)W)
                v = xb[((size_t)(c0 + cc) * H + gy) * W + gx];
            xs[cc][r][col] = v;
        }
        for (int idx = tid; idx < W_ELEMS; idx += 256) {
            int o = idx / (CCF * 9), rem = idx - o * (CCF * 9);
            int cc = rem / 9, tap = rem - cc * 9;
            size_t base = ((size_t)(o0 + o) * C + (c0 + cc)) * 9 + tap;
            ws_s[o][cc][tap] = a0 * weight[base] + a1 * weight[(size_t)1 * O * C * 9 + base]
                             + a2 * weight[(size_t)2 * O * C * 9 + base]
                             + a3 * weight[(size_t)3 * O * C * 9 + base];
        }
        __syncthreads();
        #pragma unroll
        for (int cc = 0; cc < CCF; ++cc) {
            float xv[3][10];
            #pragma unroll
            for (int dy = 0; dy < 3; ++dy)
                #pragma unroll
                for (int j = 0; j < 10; ++j) xv[dy][j] = xs[cc][ty + dy][8 * tx + j];
            #pragma unroll
            for (int o = 0; o < OT; ++o) {
                float4 w0 = *(const float4*)&ws_s[o][cc][0];
                float4 w1 = *(const float4*)&ws_s[o][cc][4];
                float w8 = ws_s[o][cc][8];
                #pragma unroll
                for (int p = 0; p < PX; ++p) {
                    float s = acc[o][p];
                    s = fmaf(xv[0][p + 0], w0.x, s); s = fmaf(xv[0][p + 1], w0.y, s);
                    s = fmaf(xv[0][p + 2], w0.z, s); s = fmaf(xv[1][p + 0], w0.w, s);
                    s = fmaf(xv[1][p + 1], w1.x, s); s = fmaf(xv[1][p + 2], w1.y, s);
                    s = fmaf(xv[2][p + 0], w1.z, s); s = fmaf(xv[2][p + 1], w1.w, s);
                    s = fmaf(xv[2][p + 2], w8, s);
                    acc[o][p] = s;
                }
            }
        }
    }
    const int oy = ty0 + ty, ox = 8 * tx;
    #pragma unroll
    for (int o = 0; o < OT; ++o) {
        float ab = a0 * bias[0 * O + o0 + o] + a1 * bias[1 * O + o0 + o]
                 + a2 * bias[2 * O + o0 + o] + a3 * bias[3 * O + o0 + o];
        float4 v0 = make_float4(acc[o][0] + ab, acc[o][1] + ab, acc[o][2] + ab, acc[o][3] + ab);
        float4 v1 = make_float4(acc[o][4] + ab, acc[o][5] + ab, acc[o][6] + ab, acc[o][7] + ab);
        float* op = out + (((size_t)b * O + (o0 + o)) * H + oy) * W + ox;
        *(float4*)(op) = v0; *(float4*)(op + 4) = v1;
    }
}

// ---------------------------------------------------------------------------
extern "C" void kernel_launch(void* const* d_in, const int* in_sizes, int n_in,
                              void* d_out, int out_size, void* d_ws, size_t ws_size,
                              hipStream_t stream) {
    const float* x      = (const float*)d_in[0];
    const float* w_fc1  = (const float*)d_in[1];
    const float* w_fc2  = (const float*)d_in[2];
    const float* b_fc2  = (const float*)d_in[3];
    const float* weight = (const float*)d_in[4];
    const float* bias   = (const float*)d_in[5];
    float* out = (float*)d_out;

    float* pooled = (float*)d_ws;                            // B*C fp32
    float* att    = pooled + B * C;
    ushort_t* wagg_sw = (ushort_t*)((char*)d_ws + 32 * 1024);
    const size_t wagg_bytes = (size_t)B * 16 * 9 * 8 * 512 * 2;      // 18,874,368
    const size_t needed = 32 * 1024 + wagg_bytes;

    pool_kernel<<<dim3(B * C), dim3(256), 0, stream>>>(x, pooled);
    attention_kernel<<<dim3(B), dim3(128), 0, stream>>>(pooled, w_fc1, w_fc2, b_fc2, att);

    if (ws_size >= needed) {
        wagg_kernel<<<dim3(O), dim3(256), 0, stream>>>(weight, att, wagg_sw);
        conv_mfma_kernel<<<dim3(B, 16, 2), dim3(256), 0, stream>>>(x, wagg_sw, bias, att, out);
    } else {
        conv_kernel<<<dim3(H / TILE_H, O / OT, B), dim3(256), 0, stream>>>(x, weight, bias, att, out);
    }
}